// Round 8
// baseline (452.952 us; speedup 1.0000x reference)
//
#include <hip/hip_runtime.h>
#include <math.h>

#define Bq 8
#define Mq 8192
#define Dq 1024
#define Nq 128
#define Fq 4096

typedef __bf16 bf16x8 __attribute__((ext_vector_type(8)));
typedef float f32x4 __attribute__((ext_vector_type(4)));
union P4 { __bf16 h[4]; unsigned long long u; };
union H4 { short4 v; _Float16 h[4]; };
union B8 { int4 v; __bf16 h[8]; };

// swizzled LDS offset, rows of 64 bf16 (128 B). XOR byte-bits 4-6 with
// (row&7)^((row>>3)&7): optimal (8 lanes/quad) for both fragment reads and
// the 4-consecutive-row packed transpose writes in xi. Bijective per row.
__device__ __forceinline__ int swz128(int row, int bcol) {
  return row * 128 + (bcol ^ ((((row & 7) ^ ((row >> 3) & 7))) << 4));
}
__device__ __forceinline__ int swz256(int row, int bcol) {  // rows of 128 bf16 (256 B)
  return row * 256 + (bcol ^ ((row & 7) << 4));
}

// ---------------- weight fp32 -> bf16 ----------------
__global__ __launch_bounds__(256) void wconv(const float* __restrict__ src,
                                             unsigned long long* __restrict__ dst, long n4)
{
  long i = (long)blockIdx.x * 256 + threadIdx.x;
  if (i >= n4) return;
  float4 v = ((const float4*)src)[i];
  P4 p; p.h[0] = (__bf16)v.x; p.h[1] = (__bf16)v.y; p.h[2] = (__bf16)v.z; p.h[3] = (__bf16)v.w;
  dst[i] = p.u;
}

// ---------------- logits = X @ phi via bf16 MFMA, 64-m tiles (grid 1024 = 4 blk/CU) ----------------
// epilogue: cbuf[m][n] = row-softmax(l), eT[n][m] = exp(l) (transposed, packed stores)
__global__ __launch_bounds__(256) void logits_mfma(
    const float* __restrict__ x, const float* __restrict__ phi,
    __bf16* __restrict__ eT, __bf16* __restrict__ cbuf)
{
  __shared__ __align__(16) char sA[8192];   // x tile  [64 m][64 k]
  __shared__ __align__(16) char sP[16384];  // phi^T   [128 n][64 k]
  int mt = blockIdx.x, b = blockIdx.y;
  int m0 = mt * 64;
  int t = threadIdx.x;
  int col = t & 127, half = t >> 7;
  int w = t >> 6, l = t & 63, la = l & 15, lb = l >> 4;

  f32x4 zero = {0.f, 0.f, 0.f, 0.f};
  f32x4 acc[8];
  for (int j = 0; j < 8; ++j) acc[j] = zero;

  for (int k0 = 0; k0 < Dq; k0 += 64) {
    #pragma unroll
    for (int s = 0; s < 4; ++s) {
      int idx = t + 256 * s;
      int row = idx >> 4, c4 = idx & 15;
      float4 v = *(const float4*)(x + ((long)b * Mq + m0 + row) * Dq + k0 + c4 * 4);
      P4 p;
      p.h[0] = (__bf16)v.x; p.h[1] = (__bf16)v.y;
      p.h[2] = (__bf16)v.z; p.h[3] = (__bf16)v.w;
      *(unsigned long long*)(sA + swz128(row, c4 * 8)) = p.u;
    }
    {
      const float* Pp = phi + (long)(k0 + half * 32) * Nq + col;
      #pragma unroll
      for (int i = 0; i < 32; i += 4) {
        float a0 = Pp[(i + 0) * Nq], a1 = Pp[(i + 1) * Nq];
        float a2 = Pp[(i + 2) * Nq], a3 = Pp[(i + 3) * Nq];
        P4 p;
        p.h[0] = (__bf16)a0; p.h[1] = (__bf16)a1;
        p.h[2] = (__bf16)a2; p.h[3] = (__bf16)a3;
        *(unsigned long long*)(sP + swz128(col, 2 * (half * 32 + i))) = p.u;
      }
    }
    __syncthreads();
    #pragma unroll
    for (int sub = 0; sub < 2; ++sub) {
      int mbyte = sub * 64 + lb * 16;
      bf16x8 af = *(const bf16x8*)(sA + swz128(w * 16 + la, mbyte));
      #pragma unroll
      for (int j = 0; j < 8; ++j) {
        bf16x8 bv = *(const bf16x8*)(sP + swz128(j * 16 + la, mbyte));
        acc[j] = __builtin_amdgcn_mfma_f32_16x16x32_bf16(af, bv, acc[j], 0, 0, 0);
      }
    }
    __syncthreads();
  }
  // per-row (m) softmax denominators over 128 n (max-free, |l| <~ 6)
  float inv[4];
  #pragma unroll
  for (int r = 0; r < 4; ++r) {
    float s = 0.f;
    #pragma unroll
    for (int j = 0; j < 8; ++j) s += __expf(acc[j][r]);
    s += __shfl_xor(s, 1); s += __shfl_xor(s, 2);
    s += __shfl_xor(s, 4); s += __shfl_xor(s, 8);
    inv[r] = 1.0f / s;
  }
  __bf16* Cb = cbuf + ((long)b * Mq + m0) * Nq;
  __bf16* Eb = eT + (long)b * Nq * Mq + m0;
  #pragma unroll
  for (int j = 0; j < 8; ++j) {
    P4 p;
    #pragma unroll
    for (int r = 0; r < 4; ++r) {
      int row = w * 16 + lb * 4 + r;
      float e = __expf(acc[j][r]);
      p.h[r] = (__bf16)e;
      Cb[(long)row * Nq + j * 16 + la] = (__bf16)(e * inv[r]);
    }
    *(unsigned long long*)(Eb + (long)(j * 16 + la) * Mq + w * 16 + lb * 4) = p.u;
  }
}

// ---------------- cinv[b*128+n] = 1 / rowsum(eT) ----------------
__global__ __launch_bounds__(256) void colsum_rows(const __bf16* __restrict__ eT,
                                                   float* __restrict__ cinv)
{
  __shared__ float red[4];
  int r = blockIdx.x;
  int t = threadIdx.x;
  const __bf16* p = eT + (long)r * Mq;
  float s = 0.f;
  #pragma unroll
  for (int k = 0; k < 4; ++k) {
    B8 v; v.v = *(const int4*)(p + t * 8 + k * 2048);
    #pragma unroll
    for (int e = 0; e < 8; ++e) s += (float)v.h[e];
  }
  #pragma unroll
  for (int off = 32; off >= 1; off >>= 1) s += __shfl_down(s, off);
  if ((t & 63) == 0) red[t >> 6] = s;
  __syncthreads();
  if (t == 0) cinv[r] = 1.0f / (red[0] + red[1] + red[2] + red[3]);
}

// ---------------- xi partials: 128 n x 128 d per block, m-chunk 512 (kc of 16) ----------------
// grid 1024 (4 blk/CU), XCD-chunked; packed LDS staging; fragment-layout fp16 partials
__global__ __launch_bounds__(256) void xi_mfma(
    const __bf16* __restrict__ eT, const float* __restrict__ x,
    _Float16* __restrict__ part)
{
  __shared__ __align__(16) char sD[16384];  // eT tile [128 n][64 m]
  __shared__ __align__(16) char sX[16384];  // x^T tile [128 d][64 m]
  int lin = blockIdx.x;
  int wk = (lin & 7) * 128 + (lin >> 3);    // same-eT-slice blocks -> same XCD
  int dts = wk & 7, kc = (wk >> 3) & 15, b = wk >> 7;
  int d0 = dts * 128;
  int t = threadIdx.x;
  int w = t >> 6, l = t & 63, la = l & 15, lb = l >> 4;
  // A staging: 4 int4 per thread
  int arow = t >> 1, ahalf = t & 1;
  const __bf16* Ep0 = eT + ((long)b * Nq + arow) * Mq + kc * 512 + ahalf * 32;
  // B staging: 8 consecutive m rows, 4 consecutive d per thread
  int bmb = (w * 2 + (l >> 5)) * 8;
  int bd  = (l & 31) * 4;
  const float* Xp0 = x + ((long)b * Mq + kc * 512 + bmb) * Dq + d0 + bd;

  f32x4 zero = {0.f, 0.f, 0.f, 0.f};
  f32x4 acc[2][8];
  for (int i = 0; i < 2; ++i) for (int j = 0; j < 8; ++j) acc[i][j] = zero;

  int4 ar[4];
  float br[8][4];
  // prologue: tile 0
  #pragma unroll
  for (int q = 0; q < 4; ++q) ar[q] = *(const int4*)(Ep0 + q * 8);
  #pragma unroll
  for (int k = 0; k < 8; ++k) *(float4*)br[k] = *(const float4*)(Xp0 + (long)k * Dq);
  #pragma unroll
  for (int q = 0; q < 4; ++q) *(int4*)(sD + swz128(arow, ahalf * 64 + q * 16)) = ar[q];
  #pragma unroll
  for (int q = 0; q < 4; ++q) {
    B8 o;
    #pragma unroll
    for (int k = 0; k < 8; ++k) o.h[k] = (__bf16)br[k][q];
    *(int4*)(sX + swz128(bd + q, 2 * bmb)) = o.v;
  }

  for (int it = 0; it < 8; ++it) {
    __syncthreads();
    if (it < 7) {  // issue next tile's loads; complete under the MFMAs
      #pragma unroll
      for (int q = 0; q < 4; ++q) ar[q] = *(const int4*)(Ep0 + (it + 1) * 64 + q * 8);
      #pragma unroll
      for (int k = 0; k < 8; ++k)
        *(float4*)br[k] = *(const float4*)(Xp0 + ((long)(it + 1) * 64 + k) * Dq);
    }
    #pragma unroll
    for (int sub = 0; sub < 2; ++sub) {
      int mbyte = sub * 64 + lb * 16;
      bf16x8 af0 = *(const bf16x8*)(sD + swz128(w * 32 + la, mbyte));
      bf16x8 af1 = *(const bf16x8*)(sD + swz128(w * 32 + 16 + la, mbyte));
      #pragma unroll
      for (int j = 0; j < 8; ++j) {
        bf16x8 bv = *(const bf16x8*)(sX + swz128(j * 16 + la, mbyte));
        acc[0][j] = __builtin_amdgcn_mfma_f32_16x16x32_bf16(af0, bv, acc[0][j], 0, 0, 0);
        acc[1][j] = __builtin_amdgcn_mfma_f32_16x16x32_bf16(af1, bv, acc[1][j], 0, 0, 0);
      }
    }
    __syncthreads();
    if (it < 7) {
      #pragma unroll
      for (int q = 0; q < 4; ++q) *(int4*)(sD + swz128(arow, ahalf * 64 + q * 16)) = ar[q];
      #pragma unroll
      for (int q = 0; q < 4; ++q) {
        B8 o;
        #pragma unroll
        for (int k = 0; k < 8; ++k) o.h[k] = (__bf16)br[k][q];
        *(int4*)(sX + swz128(bd + q, 2 * bmb)) = o.v;
      }
    }
  }
  // fragment-layout packed fp16 partial store: contiguous 512 B per wave-instr
  _Float16* P = part + (((long)kc * Bq + b) * 8 + dts) * 16384;
  #pragma unroll
  for (int i = 0; i < 2; ++i)
    #pragma unroll
    for (int j = 0; j < 8; ++j) {
      H4 o;
      #pragma unroll
      for (int r = 0; r < 4; ++r) o.h[r] = (_Float16)acc[i][j][r];
      *(short4*)(P + ((w * 16 + i * 8 + j) * 64 + l) * 4) = o.v;
    }
}

// ---------------- xi reduce (fragment layout): xib[n][d] = bf16(cinv * sum_kc) ----------------
__global__ __launch_bounds__(256) void xi_reduce(const _Float16* __restrict__ part,
    const float* __restrict__ cinv, __bf16* __restrict__ xib)
{
  int s = blockIdx.x * 256 + threadIdx.x;   // 262144 fragment slots (4 vals each)
  int l = s & 63, j = (s >> 6) & 7, i = (s >> 9) & 1;
  int w = (s >> 10) & 3, dts = (s >> 12) & 7, b = s >> 15;
  const _Float16* p = part + ((long)b * 8 + dts) * 16384 + ((w * 16 + i * 8 + j) * 64 + l) * 4;
  float sum[4] = {};
  #pragma unroll
  for (int kc = 0; kc < 16; ++kc) {
    H4 v; v.v = *(const short4*)(p + (long)kc * 1048576);
    #pragma unroll
    for (int r = 0; r < 4; ++r) sum[r] += (float)v.h[r];
  }
  int lb = l >> 4, la = l & 15;
  int nbase = w * 32 + i * 16 + lb * 4;
  int d = dts * 128 + j * 16 + la;
  #pragma unroll
  for (int r = 0; r < 4; ++r) {
    int n = b * 128 + nbase + r;
    xib[(long)n * Dq + d] = (__bf16)(sum[r] * cinv[n]);
  }
}

// ---------------- generic bf16 MFMA GEMM 128x128 tile ----------------
template<int EPI, typename OT>
__global__ __launch_bounds__(256) void gemm_bf16(const __bf16* __restrict__ A,
    const __bf16* __restrict__ Bw, const float* __restrict__ bias,
    OT* __restrict__ C, int lda, int ldb, int ldc, int kLen, long strideCz)
{
  __shared__ __align__(16) char sA[16384];
  __shared__ __align__(16) char sB[16384];
  int m0 = blockIdx.x * 128, n0 = blockIdx.y * 128;
  int kbase = blockIdx.z * kLen;
  C += (long)blockIdx.z * strideCz;
  int t = threadIdx.x;
  int col = t & 127, half = t >> 7;
  int w = t >> 6, l = t & 63, la = l & 15, lb = l >> 4;

  f32x4 zero = {0.f, 0.f, 0.f, 0.f};
  f32x4 acc[2][8];
  for (int i = 0; i < 2; ++i) for (int j = 0; j < 8; ++j) acc[i][j] = zero;

  for (int kt = 0; kt < kLen; kt += 64) {
    int kp = kbase + kt;
    #pragma unroll
    for (int s = 0; s < 4; ++s) {
      int idx = t + 256 * s;
      int row = idx >> 3, c8 = idx & 7;
      *(int4*)(sA + swz128(row, c8 * 16)) =
          *(const int4*)(A + (long)(m0 + row) * lda + kp + c8 * 8);
    }
    {
      const __bf16* Bp = Bw + (long)(kp + half * 32) * ldb + n0 + col;
      #pragma unroll
      for (int i = 0; i < 32; i += 4) {
        P4 p;
        p.h[0] = Bp[(long)(i + 0) * ldb]; p.h[1] = Bp[(long)(i + 1) * ldb];
        p.h[2] = Bp[(long)(i + 2) * ldb]; p.h[3] = Bp[(long)(i + 3) * ldb];
        *(unsigned long long*)(sB + swz128(col, 2 * (half * 32 + i))) = p.u;
      }
    }
    __syncthreads();
    #pragma unroll
    for (int sub = 0; sub < 2; ++sub) {
      int mbyte = sub * 64 + lb * 16;
      bf16x8 af0 = *(const bf16x8*)(sA + swz128(w * 32 + la, mbyte));
      bf16x8 af1 = *(const bf16x8*)(sA + swz128(w * 32 + 16 + la, mbyte));
      bf16x8 bv[8];
      #pragma unroll
      for (int j = 0; j < 8; ++j)
        bv[j] = *(const bf16x8*)(sB + swz128(j * 16 + la, mbyte));
      #pragma unroll
      for (int j = 0; j < 8; ++j) {
        acc[0][j] = __builtin_amdgcn_mfma_f32_16x16x32_bf16(af0, bv[j], acc[0][j], 0, 0, 0);
        acc[1][j] = __builtin_amdgcn_mfma_f32_16x16x32_bf16(af1, bv[j], acc[1][j], 0, 0, 0);
      }
    }
    __syncthreads();
  }
  #pragma unroll
  for (int i = 0; i < 2; ++i)
    #pragma unroll
    for (int j = 0; j < 8; ++j)
      #pragma unroll
      for (int r = 0; r < 4; ++r) {
        int row = m0 + w * 32 + i * 16 + lb * 4 + r;
        int colg = n0 + j * 16 + la;
        float v = acc[i][j][r];
        if (EPI == 2) {
          v += bias[colg];
          v = 0.5f * v * (1.0f + erff(v * 0.70710678118654752f));
        }
        C[(long)row * ldc + colg] = (OT)v;
      }
}

// ---------------- G2 reduce: yiT[b][d][n] = bf16(sum_kc part + b2[d]) ----------------
__global__ __launch_bounds__(256) void g2_reduce(const float* __restrict__ part,
    const float* __restrict__ b2, __bf16* __restrict__ yiT)
{
  long idx = (long)blockIdx.x * 256 + threadIdx.x;
  int row = (int)(idx >> 10);
  int d = (int)(idx & 1023);
  float s = part[idx] + part[idx + 1048576] + part[idx + 2097152] + part[idx + 3145728] + b2[d];
  int b = row >> 7, n = row & 127;
  yiT[((long)b * Dq + d) * Nq + n] = (__bf16)s;
}

// ---------------- combine v3: c-fragments held in registers (no sC tile) ----------------
// grid 1024 = (64 mt x 8 b x 2 dt-groups); LDS 32KB (sY only); yiT reg-prefetched
__global__ __launch_bounds__(256) void combine_v3(const __bf16* __restrict__ cbuf,
    const __bf16* __restrict__ yiT, float* __restrict__ y)
{
  __shared__ __align__(16) char sY[32768];  // yi [128 d][128 n]
  int lin = blockIdx.x;
  int wk = (lin & 7) * 128 + (lin >> 3);    // same-b blocks -> same XCD (yiT L2-hot)
  int dtg = wk & 1, mt = (wk >> 1) & 63, b = wk >> 7;
  int m0 = mt * 128;
  int t = threadIdx.x;
  int w = t >> 6, l = t & 63, la = l & 15, lb = l >> 4;

  // A-fragments straight from global: 8 x 16B per lane, held in registers
  const __bf16* Cb = cbuf + ((long)b * Mq + m0 + w * 32 + la) * Nq + lb * 8;
  bf16x8 af0[4], af1[4];
  #pragma unroll
  for (int sub = 0; sub < 4; ++sub) {
    af0[sub] = *(const bf16x8*)(Cb + sub * 32);
    af1[sub] = *(const bf16x8*)(Cb + 16 * Nq + sub * 32);
  }

  int row = t >> 1, c16b = (t & 1) * 8;     // sY staging: 8 int4 per thread
  const __bf16* Yb = yiT + ((long)b * Dq + row) * Nq + c16b * 8;
  int4 yr[8];
  #pragma unroll
  for (int q = 0; q < 8; ++q)
    yr[q] = *(const int4*)(Yb + (long)(dtg * 4) * 128 * Nq + q * 8);

  f32x4 zero = {0.f, 0.f, 0.f, 0.f};
  for (int q4 = 0; q4 < 4; ++q4) {
    int dt = dtg * 4 + q4;
    __syncthreads();   // previous iteration's sY reads complete
    #pragma unroll
    for (int q = 0; q < 8; ++q)
      *(int4*)(sY + swz256(row, (c16b + q) * 16)) = yr[q];
    __syncthreads();
    if (q4 < 3) {      // prefetch next d-tile under the MFMAs
      #pragma unroll
      for (int q = 0; q < 8; ++q)
        yr[q] = *(const int4*)(Yb + (long)(dt + 1) * 128 * Nq + q * 8);
    }
    f32x4 acc[2][8];
    for (int i = 0; i < 2; ++i) for (int j = 0; j < 8; ++j) acc[i][j] = zero;
    #pragma unroll
    for (int sub = 0; sub < 4; ++sub) {
      int mbyte = sub * 64 + lb * 16;
      #pragma unroll
      for (int j = 0; j < 8; ++j) {
        bf16x8 bv = *(const bf16x8*)(sY + swz256(j * 16 + la, mbyte));
        acc[0][j] = __builtin_amdgcn_mfma_f32_16x16x32_bf16(af0[sub], bv, acc[0][j], 0, 0, 0);
        acc[1][j] = __builtin_amdgcn_mfma_f32_16x16x32_bf16(af1[sub], bv, acc[1][j], 0, 0, 0);
      }
    }
    float* Y = y + ((long)b * Mq + m0) * Dq + dt * 128;
    #pragma unroll
    for (int i = 0; i < 2; ++i)
      #pragma unroll
      for (int j = 0; j < 8; ++j)
        #pragma unroll
        for (int r = 0; r < 4; ++r)
          Y[(long)(w * 32 + i * 16 + lb * 4 + r) * Dq + j * 16 + la] = acc[i][j][r];
  }
}

extern "C" void kernel_launch(void* const* d_in, const int* in_sizes, int n_in,
                              void* d_out, int out_size, void* d_ws, size_t ws_size,
                              hipStream_t stream) {
  const float* x   = (const float*)d_in[0];
  const float* phi = (const float*)d_in[1];
  const float* W1  = (const float*)d_in[2];
  const float* b1  = (const float*)d_in[3];
  const float* W2  = (const float*)d_in[4];
  const float* b2  = (const float*)d_in[5];
  float* y = (float*)d_out;

  char* W = (char*)d_ws;
  __bf16*   cbuf   = (__bf16*)W;                      // 16 MB
  __bf16*   eT     = (__bf16*)(W + 16777216);         // 16 MB  [b][n][m]
  __bf16*   h      = eT;                              // aliases eT (dead after xi)
  _Float16* part   = (_Float16*)(W + 33554432);       // 32 MB fp16 fragment-layout (16 kc)
  float*    g2part = (float*)(W + 33554432);          // aliases part (dead after xi_reduce)
  __bf16*   W1b    = (__bf16*)(W + 67108864);         // 8 MB
  __bf16*   W2b    = (__bf16*)(W + 75497472);         // 8 MB
  __bf16*   xib    = (__bf16*)(W + 83886080);         // 2 MB
  __bf16*   yiT    = (__bf16*)(W + 85983232);         // 2 MB
  float*    cinv   = (float*)(W + 88080384);          // 4 KB

  // 0) weights -> bf16
  wconv<<<4096, 256, 0, stream>>>(W1, (unsigned long long*)W1b, 1048576);
  wconv<<<4096, 256, 0, stream>>>(W2, (unsigned long long*)W2b, 1048576);
  // 1) logits + fused epilogue -> eT (exp, transposed), cbuf (row-softmax)
  logits_mfma<<<dim3(Mq / 64, Bq), 256, 0, stream>>>(x, phi, eT, cbuf);
  // 2) token-softmax denominators
  colsum_rows<<<Bq * Nq, 256, 0, stream>>>(eT, cinv);
  // 3) xi partials (split-K 16) + reduce
  xi_mfma<<<1024, 256, 0, stream>>>(eT, x, part);
  xi_reduce<<<1024, 256, 0, stream>>>(part, cinv, xib);
  // 4) h = gelu(xi @ W1 + b1)
  gemm_bf16<2, __bf16><<<dim3(8, 32, 1), 256, 0, stream>>>(
      xib, W1b, b1, h, Dq, Fq, Fq, 1024, 0L);
  // 5) yi partials = h @ W2 (split-K 4)
  gemm_bf16<0, float><<<dim3(8, 8, 4), 256, 0, stream>>>(
      h, W2b, nullptr, g2part, Fq, Dq, Dq, 1024, 1048576L);
  // 6) reduce + b2 -> yiT bf16 [b][d][n]
  g2_reduce<<<4096, 256, 0, stream>>>(g2part, b2, yiT);
  // 7) y = c @ yi (register c-fragments, dt-loop)
  combine_v3<<<1024, 256, 0, stream>>>(cbuf, yiT, y);
}

// Round 9
// 365.139 us; speedup vs baseline: 1.2405x; 1.2405x over previous
//
#include <hip/hip_runtime.h>
#include <math.h>

#define Bq 8
#define Mq 8192
#define Dq 1024
#define Nq 128
#define Fq 4096

typedef __bf16 bf16x8 __attribute__((ext_vector_type(8)));
typedef float f32x4 __attribute__((ext_vector_type(4)));
union P4 { __bf16 h[4]; unsigned long long u; };
union H4 { short4 v; _Float16 h[4]; };
union B8 { int4 v; __bf16 h[8]; };

// swizzled LDS offsets: XOR byte-bits 4-6 with row&7 (377-µs-proven form)
__device__ __forceinline__ int swz128(int row, int bcol) {  // rows of 64 bf16 (128 B)
  return row * 128 + (bcol ^ ((row & 7) << 4));
}
__device__ __forceinline__ int swz256(int row, int bcol) {  // rows of 128 bf16 (256 B)
  return row * 256 + (bcol ^ ((row & 7) << 4));
}
// xi-local swizzle: also folds row>>3 so 4-consecutive-row packed b128 writes spread banks
__device__ __forceinline__ int swzX(int row, int bcol) {
  return row * 128 + (bcol ^ ((((row & 7) ^ ((row >> 3) & 7))) << 4));
}

// ---------------- weight fp32 -> bf16 ----------------
__global__ __launch_bounds__(256) void wconv(const float* __restrict__ src,
                                             unsigned long long* __restrict__ dst, long n4)
{
  long i = (long)blockIdx.x * 256 + threadIdx.x;
  if (i >= n4) return;
  float4 v = ((const float4*)src)[i];
  P4 p; p.h[0] = (__bf16)v.x; p.h[1] = (__bf16)v.y; p.h[2] = (__bf16)v.z; p.h[3] = (__bf16)v.w;
  dst[i] = p.u;
}

// ---------------- phi [1024 d][128 n] fp32 -> phiT [128 n][1024 d] bf16 ----------------
__global__ __launch_bounds__(256) void phi_conv(const float* __restrict__ src,
                                                __bf16* __restrict__ dst)
{
  int idx = blockIdx.x * 256 + threadIdx.x;   // 131072
  int d = idx >> 7, n = idx & 127;
  dst[(long)n * Dq + d] = (__bf16)src[idx];
}

// ---------------- logits = X @ phi via bf16 MFMA (128-m tiles, grid 512) ----------------
// B-staging from phiT: pure int4 copies. epilogue: cbuf row-softmax, eT = exp (transposed)
__global__ __launch_bounds__(256) void logits_mfma(
    const float* __restrict__ x, const __bf16* __restrict__ phiT,
    __bf16* __restrict__ eT, __bf16* __restrict__ cbuf)
{
  __shared__ __align__(16) char sA[16384];  // x tile  [128 m][64 k]
  __shared__ __align__(16) char sP[16384];  // phiT    [128 n][64 k]
  int mt = blockIdx.x, b = blockIdx.y;
  int m0 = mt * 128;
  int t = threadIdx.x;
  int arow = t >> 4, ac4 = t & 15;
  int prow = t >> 1, pc = (t & 1) * 4;
  int w = t >> 6, l = t & 63, la = l & 15, lb = l >> 4;

  f32x4 zero = {0.f, 0.f, 0.f, 0.f};
  f32x4 acc[2][8];
  for (int i = 0; i < 2; ++i) for (int j = 0; j < 8; ++j) acc[i][j] = zero;

  for (int k0 = 0; k0 < Dq; k0 += 64) {
    #pragma unroll
    for (int i = 0; i < 8; ++i) {
      int row = arow + 16 * i;
      float4 v = *(const float4*)(x + ((long)b * Mq + m0 + row) * Dq + k0 + ac4 * 4);
      P4 p;
      p.h[0] = (__bf16)v.x; p.h[1] = (__bf16)v.y;
      p.h[2] = (__bf16)v.z; p.h[3] = (__bf16)v.w;
      *(unsigned long long*)(sA + swz128(row, 8 * ac4)) = p.u;
    }
    {
      const __bf16* Pp = phiT + (long)prow * Dq + k0 + pc * 8;
      #pragma unroll
      for (int q = 0; q < 4; ++q)
        *(int4*)(sP + swz128(prow, (pc + q) * 16)) = *(const int4*)(Pp + q * 8);
    }
    __syncthreads();
    #pragma unroll
    for (int sub = 0; sub < 2; ++sub) {
      int mbyte = sub * 64 + lb * 16;
      bf16x8 af0 = *(const bf16x8*)(sA + swz128(w * 32 + la, mbyte));
      bf16x8 af1 = *(const bf16x8*)(sA + swz128(w * 32 + 16 + la, mbyte));
      bf16x8 bv[8];
      #pragma unroll
      for (int j = 0; j < 8; ++j)
        bv[j] = *(const bf16x8*)(sP + swz128(j * 16 + la, mbyte));
      #pragma unroll
      for (int j = 0; j < 8; ++j) {
        acc[0][j] = __builtin_amdgcn_mfma_f32_16x16x32_bf16(af0, bv[j], acc[0][j], 0, 0, 0);
        acc[1][j] = __builtin_amdgcn_mfma_f32_16x16x32_bf16(af1, bv[j], acc[1][j], 0, 0, 0);
      }
    }
    __syncthreads();
  }
  // per-row (m) softmax denominators over 128 n (max-free, |l| <~ 6)
  float inv[2][4];
  #pragma unroll
  for (int i = 0; i < 2; ++i)
    #pragma unroll
    for (int r = 0; r < 4; ++r) {
      float s = 0.f;
      #pragma unroll
      for (int j = 0; j < 8; ++j) s += __expf(acc[i][j][r]);
      s += __shfl_xor(s, 1); s += __shfl_xor(s, 2);
      s += __shfl_xor(s, 4); s += __shfl_xor(s, 8);
      inv[i][r] = 1.0f / s;
    }
  __bf16* Cb = cbuf + ((long)b * Mq + m0) * Nq;
  __bf16* Eb = eT + (long)b * Nq * Mq + m0;
  #pragma unroll
  for (int i = 0; i < 2; ++i)
    #pragma unroll
    for (int j = 0; j < 8; ++j) {
      P4 p;
      #pragma unroll
      for (int r = 0; r < 4; ++r) {
        int row = w * 32 + i * 16 + lb * 4 + r;
        float e = __expf(acc[i][j][r]);
        p.h[r] = (__bf16)e;
        Cb[(long)row * Nq + j * 16 + la] = (__bf16)(e * inv[i][r]);
      }
      *(unsigned long long*)(Eb + (long)(j * 16 + la) * Mq + w * 32 + i * 16 + lb * 4) = p.u;
    }
}

// ---------------- cinv[b*128+n] = 1 / rowsum(eT) ----------------
__global__ __launch_bounds__(256) void colsum_rows(const __bf16* __restrict__ eT,
                                                   float* __restrict__ cinv)
{
  __shared__ float red[4];
  int r = blockIdx.x;
  int t = threadIdx.x;
  const __bf16* p = eT + (long)r * Mq;
  float s = 0.f;
  #pragma unroll
  for (int k = 0; k < 4; ++k) {
    B8 v; v.v = *(const int4*)(p + t * 8 + k * 2048);
    #pragma unroll
    for (int e = 0; e < 8; ++e) s += (float)v.h[e];
  }
  #pragma unroll
  for (int off = 32; off >= 1; off >>= 1) s += __shfl_down(s, off);
  if ((t & 63) == 0) red[t >> 6] = s;
  __syncthreads();
  if (t == 0) cinv[r] = 1.0f / (red[0] + red[1] + red[2] + red[3]);
}

// ---------------- xi partials: 128 n x 128 d per block, m-chunk 1024 (kc of 8) ----------------
// grid 512, XCD-chunked; packed b128 staging (swzX); fragment-layout fp16 partials
__global__ __launch_bounds__(256) void xi_mfma(
    const __bf16* __restrict__ eT, const float* __restrict__ x,
    _Float16* __restrict__ part)
{
  __shared__ __align__(16) char sD[16384];  // eT tile [128 n][64 m]
  __shared__ __align__(16) char sX[16384];  // x^T tile [128 d][64 m]
  int lin = blockIdx.x;
  int wk = (lin & 7) * 64 + (lin >> 3);     // same-eT-chunk blocks -> same XCD
  int dts = wk & 7, kc = (wk >> 3) & 7, b = wk >> 6;
  int d0 = dts * 128;
  int t = threadIdx.x;
  int w = t >> 6, l = t & 63, la = l & 15, lb = l >> 4;
  // A staging: 4 int4 per thread
  int arow = t >> 1, ahalf = t & 1;
  const __bf16* Ep0 = eT + ((long)b * Nq + arow) * Mq + kc * 1024 + ahalf * 32;
  // B staging: 8 consecutive m rows x 4 consecutive d per thread, packed to 4 b128
  int bmb = (w * 2 + (l >> 5)) * 8;
  int bd  = (l & 31) * 4;
  const float* Xp0 = x + ((long)b * Mq + kc * 1024 + bmb) * Dq + d0 + bd;

  f32x4 zero = {0.f, 0.f, 0.f, 0.f};
  f32x4 acc[2][8];
  for (int i = 0; i < 2; ++i) for (int j = 0; j < 8; ++j) acc[i][j] = zero;

  int4 ar[4];
  float br[8][4];
  // prologue: tile 0
  #pragma unroll
  for (int q = 0; q < 4; ++q) ar[q] = *(const int4*)(Ep0 + q * 8);
  #pragma unroll
  for (int k = 0; k < 8; ++k) *(float4*)br[k] = *(const float4*)(Xp0 + (long)k * Dq);
  #pragma unroll
  for (int q = 0; q < 4; ++q) *(int4*)(sD + swzX(arow, ahalf * 64 + q * 16)) = ar[q];
  #pragma unroll
  for (int q = 0; q < 4; ++q) {
    B8 o;
    #pragma unroll
    for (int k = 0; k < 8; ++k) o.h[k] = (__bf16)br[k][q];
    *(int4*)(sX + swzX(bd + q, 2 * bmb)) = o.v;
  }

  for (int it = 0; it < 16; ++it) {
    __syncthreads();
    if (it < 15) {  // issue next tile's loads; they complete under the MFMAs
      #pragma unroll
      for (int q = 0; q < 4; ++q) ar[q] = *(const int4*)(Ep0 + (it + 1) * 64 + q * 8);
      #pragma unroll
      for (int k = 0; k < 8; ++k)
        *(float4*)br[k] = *(const float4*)(Xp0 + ((long)(it + 1) * 64 + k) * Dq);
    }
    #pragma unroll
    for (int sub = 0; sub < 2; ++sub) {
      int mbyte = sub * 64 + lb * 16;
      bf16x8 af0 = *(const bf16x8*)(sD + swzX(w * 32 + la, mbyte));
      bf16x8 af1 = *(const bf16x8*)(sD + swzX(w * 32 + 16 + la, mbyte));
      #pragma unroll
      for (int j = 0; j < 8; ++j) {
        bf16x8 bv = *(const bf16x8*)(sX + swzX(j * 16 + la, mbyte));
        acc[0][j] = __builtin_amdgcn_mfma_f32_16x16x32_bf16(af0, bv, acc[0][j], 0, 0, 0);
        acc[1][j] = __builtin_amdgcn_mfma_f32_16x16x32_bf16(af1, bv, acc[1][j], 0, 0, 0);
      }
    }
    __syncthreads();
    if (it < 15) {
      #pragma unroll
      for (int q = 0; q < 4; ++q) *(int4*)(sD + swzX(arow, ahalf * 64 + q * 16)) = ar[q];
      #pragma unroll
      for (int q = 0; q < 4; ++q) {
        B8 o;
        #pragma unroll
        for (int k = 0; k < 8; ++k) o.h[k] = (__bf16)br[k][q];
        *(int4*)(sX + swzX(bd + q, 2 * bmb)) = o.v;
      }
    }
  }
  // fragment-layout packed fp16 partial store: 512 B contiguous per wave-instr
  _Float16* P = part + (((long)kc * Bq + b) * 8 + dts) * 16384;
  #pragma unroll
  for (int i = 0; i < 2; ++i)
    #pragma unroll
    for (int j = 0; j < 8; ++j) {
      H4 o;
      #pragma unroll
      for (int r = 0; r < 4; ++r) o.h[r] = (_Float16)acc[i][j][r];
      *(short4*)(P + ((w * 16 + i * 8 + j) * 64 + l) * 4) = o.v;
    }
}

// ---------------- xi reduce (fragment layout): xib[n][d] = bf16(cinv * sum_kc) ----------------
__global__ __launch_bounds__(256) void xi_reduce(const _Float16* __restrict__ part,
    const float* __restrict__ cinv, __bf16* __restrict__ xib)
{
  int s = blockIdx.x * 256 + threadIdx.x;   // 262144 fragment slots (4 vals each)
  int l = s & 63, j = (s >> 6) & 7, i = (s >> 9) & 1;
  int w = (s >> 10) & 3, dts = (s >> 12) & 7, b = s >> 15;
  const _Float16* p = part + ((long)b * 8 + dts) * 16384 + ((w * 16 + i * 8 + j) * 64 + l) * 4;
  float sum[4] = {};
  #pragma unroll
  for (int kc = 0; kc < 8; ++kc) {
    H4 v; v.v = *(const short4*)(p + (long)kc * 1048576);
    #pragma unroll
    for (int r = 0; r < 4; ++r) sum[r] += (float)v.h[r];
  }
  int lb = l >> 4, la = l & 15;
  int nbase = w * 32 + i * 16 + lb * 4;
  int d = dts * 128 + j * 16 + la;
  #pragma unroll
  for (int r = 0; r < 4; ++r) {
    int n = b * 128 + nbase + r;
    xib[(long)n * Dq + d] = (__bf16)(sum[r] * cinv[n]);
  }
}

// ---------------- generic bf16 MFMA GEMM 128x128 tile ----------------
template<int EPI, typename OT>
__global__ __launch_bounds__(256) void gemm_bf16(const __bf16* __restrict__ A,
    const __bf16* __restrict__ Bw, const float* __restrict__ bias,
    OT* __restrict__ C, int lda, int ldb, int ldc, int kLen, long strideCz)
{
  __shared__ __align__(16) char sA[16384];
  __shared__ __align__(16) char sB[16384];
  int m0 = blockIdx.x * 128, n0 = blockIdx.y * 128;
  int kbase = blockIdx.z * kLen;
  C += (long)blockIdx.z * strideCz;
  int t = threadIdx.x;
  int col = t & 127, half = t >> 7;
  int w = t >> 6, l = t & 63, la = l & 15, lb = l >> 4;

  f32x4 zero = {0.f, 0.f, 0.f, 0.f};
  f32x4 acc[2][8];
  for (int i = 0; i < 2; ++i) for (int j = 0; j < 8; ++j) acc[i][j] = zero;

  for (int kt = 0; kt < kLen; kt += 64) {
    int kp = kbase + kt;
    #pragma unroll
    for (int s = 0; s < 4; ++s) {
      int idx = t + 256 * s;
      int row = idx >> 3, c8 = idx & 7;
      *(int4*)(sA + swz128(row, c8 * 16)) =
          *(const int4*)(A + (long)(m0 + row) * lda + kp + c8 * 8);
    }
    {
      const __bf16* Bp = Bw + (long)(kp + half * 32) * ldb + n0 + col;
      #pragma unroll
      for (int i = 0; i < 32; i += 4) {
        P4 p;
        p.h[0] = Bp[(long)(i + 0) * ldb]; p.h[1] = Bp[(long)(i + 1) * ldb];
        p.h[2] = Bp[(long)(i + 2) * ldb]; p.h[3] = Bp[(long)(i + 3) * ldb];
        *(unsigned long long*)(sB + swz128(col, 2 * (half * 32 + i))) = p.u;
      }
    }
    __syncthreads();
    #pragma unroll
    for (int sub = 0; sub < 2; ++sub) {
      int mbyte = sub * 64 + lb * 16;
      bf16x8 af0 = *(const bf16x8*)(sA + swz128(w * 32 + la, mbyte));
      bf16x8 af1 = *(const bf16x8*)(sA + swz128(w * 32 + 16 + la, mbyte));
      bf16x8 bv[8];
      #pragma unroll
      for (int j = 0; j < 8; ++j)
        bv[j] = *(const bf16x8*)(sB + swz128(j * 16 + la, mbyte));
      #pragma unroll
      for (int j = 0; j < 8; ++j) {
        acc[0][j] = __builtin_amdgcn_mfma_f32_16x16x32_bf16(af0, bv[j], acc[0][j], 0, 0, 0);
        acc[1][j] = __builtin_amdgcn_mfma_f32_16x16x32_bf16(af1, bv[j], acc[1][j], 0, 0, 0);
      }
    }
    __syncthreads();
  }
  #pragma unroll
  for (int i = 0; i < 2; ++i)
    #pragma unroll
    for (int j = 0; j < 8; ++j)
      #pragma unroll
      for (int r = 0; r < 4; ++r) {
        int row = m0 + w * 32 + i * 16 + lb * 4 + r;
        int colg = n0 + j * 16 + la;
        float v = acc[i][j][r];
        if (EPI == 2) {
          v += bias[colg];
          v = 0.5f * v * (1.0f + erff(v * 0.70710678118654752f));
        }
        C[(long)row * ldc + colg] = (OT)v;
      }
}

// ---------------- G2 reduce: yiT[b][d][n] = bf16(sum_kc part + b2[d]) ----------------
__global__ __launch_bounds__(256) void g2_reduce(const float* __restrict__ part,
    const float* __restrict__ b2, __bf16* __restrict__ yiT)
{
  long idx = (long)blockIdx.x * 256 + threadIdx.x;
  int row = (int)(idx >> 10);
  int d = (int)(idx & 1023);
  float s = part[idx] + part[idx + 1048576] + part[idx + 2097152] + part[idx + 3145728] + b2[d];
  int b = row >> 7, n = row & 127;
  yiT[((long)b * Dq + d) * Nq + n] = (__bf16)s;
}

// ---------------- combine: y[b,m,d] = sum_n cbuf[m,n] * yiT[d,n] ----------------
// 1D grid 4096, dt-fastest work order + XCD-chunked swizzle (377-µs-proven form)
__global__ __launch_bounds__(256) void combine_mfma(const __bf16* __restrict__ cbuf,
    const __bf16* __restrict__ yiT, float* __restrict__ y)
{
  __shared__ __align__(16) char sC[32768];  // c  [128 m][128 n]
  __shared__ __align__(16) char sY[32768];  // yi [128 d][128 n]
  int lin = blockIdx.x;
  int wk = (lin & 7) * 512 + (lin >> 3);
  int dt = wk & 7, mt = (wk >> 3) & 63, b = wk >> 9;
  int m0 = mt * 128, d0 = dt * 128;
  int t = threadIdx.x;
  #pragma unroll
  for (int s = 0; s < 8; ++s) {
    int idx = t + 256 * s;
    int row = idx >> 4, c16 = idx & 15;
    *(int4*)(sC + swz256(row, c16 * 16)) =
        *(const int4*)(cbuf + ((long)b * Mq + m0 + row) * Nq + c16 * 8);
    *(int4*)(sY + swz256(row, c16 * 16)) =
        *(const int4*)(yiT + ((long)b * Dq + d0 + row) * Nq + c16 * 8);
  }
  __syncthreads();
  int w = t >> 6, l = t & 63, la = l & 15, lb = l >> 4;
  f32x4 zero = {0.f, 0.f, 0.f, 0.f};
  f32x4 acc[2][8];
  for (int i = 0; i < 2; ++i) for (int j = 0; j < 8; ++j) acc[i][j] = zero;
  #pragma unroll
  for (int sub = 0; sub < 4; ++sub) {
    int mbyte = sub * 64 + lb * 16;
    bf16x8 af0 = *(const bf16x8*)(sC + swz256(w * 32 + la, mbyte));
    bf16x8 af1 = *(const bf16x8*)(sC + swz256(w * 32 + 16 + la, mbyte));
    #pragma unroll
    for (int j = 0; j < 8; ++j) {
      bf16x8 bv = *(const bf16x8*)(sY + swz256(j * 16 + la, mbyte));
      acc[0][j] = __builtin_amdgcn_mfma_f32_16x16x32_bf16(af0, bv, acc[0][j], 0, 0, 0);
      acc[1][j] = __builtin_amdgcn_mfma_f32_16x16x32_bf16(af1, bv, acc[1][j], 0, 0, 0);
    }
  }
  float* Y = y + ((long)b * Mq + m0) * Dq + d0;
  #pragma unroll
  for (int i = 0; i < 2; ++i)
    #pragma unroll
    for (int j = 0; j < 8; ++j)
      #pragma unroll
      for (int r = 0; r < 4; ++r)
        Y[(long)(w * 32 + i * 16 + lb * 4 + r) * Dq + j * 16 + la] = acc[i][j][r];
}

extern "C" void kernel_launch(void* const* d_in, const int* in_sizes, int n_in,
                              void* d_out, int out_size, void* d_ws, size_t ws_size,
                              hipStream_t stream) {
  const float* x   = (const float*)d_in[0];
  const float* phi = (const float*)d_in[1];
  const float* W1  = (const float*)d_in[2];
  const float* b1  = (const float*)d_in[3];
  const float* W2  = (const float*)d_in[4];
  const float* b2  = (const float*)d_in[5];
  float* y = (float*)d_out;

  char* W = (char*)d_ws;
  __bf16*   cbuf   = (__bf16*)W;                      // 16 MB
  __bf16*   eT     = (__bf16*)(W + 16777216);         // 16 MB  [b][n][m]
  __bf16*   h      = eT;                              // aliases eT (dead after xi)
  _Float16* part   = (_Float16*)(W + 33554432);       // 16 MB fp16 fragment-layout
  float*    g2part = (float*)(W + 33554432);          // aliases part (dead after xi_reduce)
  __bf16*   W1b    = (__bf16*)(W + 50331648);         // 8 MB
  __bf16*   W2b    = (__bf16*)(W + 58720256);         // 8 MB
  __bf16*   xib    = (__bf16*)(W + 67108864);         // 2 MB
  __bf16*   yiT    = (__bf16*)(W + 69206016);         // 2 MB
  float*    cinv   = (float*)(W + 71303168);          // 4 KB
  __bf16*   phiT   = (__bf16*)(W + 75497472);         // 256 KB [n][d] bf16

  // 0) weights -> bf16; phi -> transposed bf16
  wconv<<<4096, 256, 0, stream>>>(W1, (unsigned long long*)W1b, 1048576);
  wconv<<<4096, 256, 0, stream>>>(W2, (unsigned long long*)W2b, 1048576);
  phi_conv<<<512, 256, 0, stream>>>(phi, phiT);
  // 1) logits + fused epilogue -> eT (exp, transposed), cbuf (row-softmax)
  logits_mfma<<<dim3(Mq / 128, Bq), 256, 0, stream>>>(x, phiT, eT, cbuf);
  // 2) token-softmax denominators
  colsum_rows<<<Bq * Nq, 256, 0, stream>>>(eT, cinv);
  // 3) xi partials (split-K 8, fragment-layout fp16) + reduce
  xi_mfma<<<512, 256, 0, stream>>>(eT, x, part);
  xi_reduce<<<1024, 256, 0, stream>>>(part, cinv, xib);
  // 4) h = gelu(xi @ W1 + b1)
  gemm_bf16<2, __bf16><<<dim3(8, 32, 1), 256, 0, stream>>>(
      xib, W1b, b1, h, Dq, Fq, Fq, 1024, 0L);
  // 5) yi partials = h @ W2 (split-K 4)
  gemm_bf16<0, float><<<dim3(8, 8, 4), 256, 0, stream>>>(
      h, W2b, nullptr, g2part, Fq, Dq, Dq, 1024, 1048576L);
  // 6) reduce + b2 -> yiT bf16 [b][d][n]
  g2_reduce<<<4096, 256, 0, stream>>>(g2part, b2, yiT);
  // 7) y = c @ yi (dt-loop 1D-swizzled combine)
  combine_mfma<<<4096, 256, 0, stream>>>(cbuf, yiT, y);
}